// Round 4
// baseline (126.098 us; speedup 1.0000x reference)
//
#include <hip/hip_runtime.h>
#include <hip/hip_bf16.h>

typedef __bf16 bf16x8 __attribute__((ext_vector_type(8)));
typedef float  f32x4  __attribute__((ext_vector_type(4)));

static constexpr int D     = 128;
static constexpr int BATCH = 4096;
static constexpr int N     = 8192;
static constexpr int WT    = 64;              // wave tile (one wave per block)
static constexpr int NT    = N / WT;          // 128
static constexpr int TRI   = NT * (NT + 1) / 2; // 8256

// ---------------- prep: fp32 -> bf16 copy + row norms + zero out ----------------
__global__ __launch_bounds__(256) void prep_kernel(const float* __restrict__ f,
                                                   unsigned short* __restrict__ fb,
                                                   float* __restrict__ norms,
                                                   float* __restrict__ out) {
    if (blockIdx.x == 0 && threadIdx.x == 0) out[0] = 0.f;
    const int w = threadIdx.x >> 6, lane = threadIdx.x & 63;
    const int row = blockIdx.x * 4 + w;
    const float2 v = *(const float2*)(f + (size_t)row * D + lane * 2);
    union { __bf16 h[2]; unsigned int u; } pk;
    pk.h[0] = (__bf16)v.x; pk.h[1] = (__bf16)v.y;
    *(unsigned int*)(fb + (size_t)row * D + lane * 2) = pk.u;
    float s = v.x * v.x + v.y * v.y;
    #pragma unroll
    for (int m = 1; m <= 32; m <<= 1) s += __shfl_xor(s, m);
    if (lane == 0) norms[row] = s;
}

// ---------------- per-wave 64x64 Gram tile, operands straight from L2 ----------------
// Lower triangle of unified 8192x8192 Gram. Block (ti,tj), tj<=ti.
//   row partials  -> Prow[ti][tj][0..64)        (slots [0,128))
//   col partials  -> Prow[tj][128+ti][0..64)    (slots [128,256)), skipped for diag
//   stripe ti==tj+64 holds sim_ab diagonal -> diag[]
__global__ __launch_bounds__(64, 3) void wave_kernel(const unsigned short* __restrict__ fbf,
                                                     const float* __restrict__ norms,
                                                     float* __restrict__ Prow,
                                                     float* __restrict__ diag) {
    const int id = blockIdx.x;
    int ti = (int)((sqrtf(8.f * (float)id + 1.f) - 1.f) * 0.5f);
    while ((ti + 1) * (ti + 2) / 2 <= id) ++ti;
    while (ti * (ti + 1) / 2 > id) --ti;
    const int tj = id - ti * (ti + 1) / 2;
    const bool diagblk = (ti == tj);
    const bool stripe  = (ti == tj + 64);

    const int lane = threadIdx.x;
    const int lr = lane & 15, hk = lane >> 4;

    const unsigned char* Ab = (const unsigned char*)fbf + (size_t)ti * WT * 256; // 256B/row
    const unsigned char* Bb = (const unsigned char*)fbf + (size_t)tj * WT * 256;

    f32x4 acc[4][4];
    #pragma unroll
    for (int i = 0; i < 4; ++i)
        #pragma unroll
        for (int j = 0; j < 4; ++j)
            acc[i][j] = (f32x4){0.f, 0.f, 0.f, 0.f};

    #pragma unroll
    for (int ks = 0; ks < 4; ++ks) {
        const int ko = (ks * 4 + hk) * 16;   // byte offset of this lane's 8-elem k-chunk
        bf16x8 av[4], bv[4];
        #pragma unroll
        for (int fi = 0; fi < 4; ++fi)
            av[fi] = *(const bf16x8*)(Ab + (fi * 16 + lr) * 256 + ko);
        #pragma unroll
        for (int fj = 0; fj < 4; ++fj)
            bv[fj] = *(const bf16x8*)(Bb + (fj * 16 + lr) * 256 + ko);
        #pragma unroll
        for (int fi = 0; fi < 4; ++fi)
            #pragma unroll
            for (int fj = 0; fj < 4; ++fj)
                acc[fi][fj] = __builtin_amdgcn_mfma_f32_16x16x32_bf16(av[fi], bv[fj], acc[fi][fj], 0, 0, 0);
    }

    // norms (L1/L2-hit scalar loads)
    float rowN[4][4], colN[4];
    #pragma unroll
    for (int fi = 0; fi < 4; ++fi)
        #pragma unroll
        for (int r = 0; r < 4; ++r)
            rowN[fi][r] = norms[ti * WT + fi * 16 + hk * 4 + r];
    #pragma unroll
    for (int fj = 0; fj < 4; ++fj)
        colN[fj] = norms[tj * WT + fj * 16 + lr];

    // dot -> cauchy sim in-register; diagonal handling
    #pragma unroll
    for (int fi = 0; fi < 4; ++fi) {
        const int lrow = fi * 16 + hk * 4;   // + r
        #pragma unroll
        for (int fj = 0; fj < 4; ++fj) {
            const int lcol = fj * 16 + lr;
            #pragma unroll
            for (int r = 0; r < 4; ++r) {
                float sq = rowN[fi][r] + colN[fj] - 2.f * acc[fi][fj][r];
                sq = fmaxf(sq, 0.f);
                float sim = __builtin_amdgcn_rcpf(sq + 1.f);
                if (diagblk && (lrow + r == lcol)) sim = 0.f;              // self-mask
                if (stripe && (lrow + r == lcol)) diag[tj * WT + lcol] = sim; // ab diag
                acc[fi][fj][r] = sim;
            }
        }
    }

    // row partials: sum over fj + 16-lane tree; lanes lr==0 store float4 (coalesced 64B)
    float* PR = Prow + ((size_t)ti * 256 + tj) * WT;
    #pragma unroll
    for (int fi = 0; fi < 4; ++fi) {
        f32x4 rs;
        #pragma unroll
        for (int r = 0; r < 4; ++r)
            rs[r] = acc[fi][0][r] + acc[fi][1][r] + acc[fi][2][r] + acc[fi][3][r];
        #pragma unroll
        for (int r = 0; r < 4; ++r) {
            rs[r] += __shfl_xor(rs[r], 1);
            rs[r] += __shfl_xor(rs[r], 2);
            rs[r] += __shfl_xor(rs[r], 4);
            rs[r] += __shfl_xor(rs[r], 8);
        }
        if (lr == 0)
            *(f32x4*)(PR + fi * 16 + hk * 4) = rs;
    }

    // col partials (off-diag blocks): sum over fi,r + cross-half tree; hk==0 lanes store
    if (!diagblk) {
        float* PC = Prow + ((size_t)tj * 256 + 128 + ti) * WT;
        #pragma unroll
        for (int fj = 0; fj < 4; ++fj) {
            float cs = 0.f;
            #pragma unroll
            for (int fi = 0; fi < 4; ++fi)
                #pragma unroll
                for (int r = 0; r < 4; ++r)
                    cs += acc[fi][fj][r];
            cs += __shfl_xor(cs, 16);
            cs += __shfl_xor(cs, 32);
            if (hk == 0)
                PC[fj * 16 + lr] = cs;
        }
    }
}

// ---------------- finalize: per row-tile, sum valid slots, logs, scalar ----------------
__global__ __launch_bounds__(64) void finalize_kernel(const float* __restrict__ Prow,
                                                      const float* __restrict__ diag,
                                                      float* __restrict__ out) {
    const int t = blockIdx.x;       // 128 row-tiles
    const int r = threadIdx.x;      // 64 rows per tile
    const float* base = Prow + (size_t)t * 256 * WT + r;
    float s = 0.f;
    for (int k = 0; k <= t; ++k)          s += base[k * WT];          // row-side slots
    for (int k = 129 + t; k < 256; ++k)   s += base[k * WT];          // col-side slots
    const int i = t * WT + r;
    float term = 0.5f * __logf(s);
    if (i >= BATCH) term -= __logf(diag[i - BATCH]);
    #pragma unroll
    for (int m = 1; m <= 32; m <<= 1) term += __shfl_xor(term, m);
    if (r == 0)
        atomicAdd(out, term / (float)BATCH);
}

extern "C" void kernel_launch(void* const* d_in, const int* in_sizes, int n_in,
                              void* d_out, int out_size, void* d_ws, size_t ws_size,
                              hipStream_t stream) {
    const float* feat = (const float*)d_in[0];
    char* ws = (char*)d_ws;
    // ws layout: fbf16 2MB @0 | norms 32KB @2MB | diag 16KB | Prow 8MB
    unsigned short* fbf = (unsigned short*)ws;
    float* norms = (float*)(ws + (2u << 20));
    float* diag  = (float*)(ws + (2u << 20) + 32768);
    float* Prow  = (float*)(ws + (2u << 20) + 65536);
    float* out   = (float*)d_out;

    prep_kernel<<<N / 4, 256, 0, stream>>>(feat, fbf, norms, out);
    wave_kernel<<<TRI, 64, 0, stream>>>(fbf, norms, Prow, diag);
    finalize_kernel<<<NT, 64, 0, stream>>>(Prow, diag, out);
}

// Round 5
// 104.784 us; speedup vs baseline: 1.2034x; 1.2034x over previous
//
#include <hip/hip_runtime.h>
#include <hip/hip_bf16.h>

typedef __bf16 bf16x8 __attribute__((ext_vector_type(8)));
typedef float  f32x4  __attribute__((ext_vector_type(4)));

static constexpr int D     = 128;
static constexpr int BATCH = 4096;
static constexpr int N     = 8192;
static constexpr int BT    = 256;
static constexpr int NT    = 32;               // N / BT
static constexpr int TRI   = NT * (NT + 1) / 2; // 528
static constexpr int NBLK  = TRI / 3;           // 176 blocks x 3 tiles

__device__ __forceinline__ void load_lds16(const void* g, void* l) {
    __builtin_amdgcn_global_load_lds(
        (const __attribute__((address_space(1))) unsigned int*)g,
        (__attribute__((address_space(3))) unsigned int*)l, 16, 0, 0);
}

#define WAITV(n) do { asm volatile("s_waitcnt vmcnt(" #n ")" ::: "memory"); \
                      __builtin_amdgcn_sched_barrier(0); } while (0)
#define BAR()    do { __builtin_amdgcn_s_barrier(); \
                      __builtin_amdgcn_sched_barrier(0); } while (0)
#define LGKM0()  do { asm volatile("s_waitcnt lgkmcnt(0)" ::: "memory"); \
                      __builtin_amdgcn_sched_barrier(0); } while (0)

// ---------------- prep: bf16 convert + norms + exact fp32 ab-diag + zero out ----------------
__global__ __launch_bounds__(256) void prep_kernel(const float* __restrict__ f,
                                                   unsigned short* __restrict__ fb,
                                                   float* __restrict__ norms,
                                                   float* __restrict__ diag,
                                                   float* __restrict__ out) {
    if (blockIdx.x == 0 && threadIdx.x == 0) out[0] = 0.f;
    const int w = threadIdx.x >> 6, lane = threadIdx.x & 63;
    const int i = blockIdx.x * 4 + w;                 // 0..4095
    const float2 va = *(const float2*)(f + (size_t)i * D + lane * 2);
    const float2 vb = *(const float2*)(f + (size_t)(i + BATCH) * D + lane * 2);
    union { __bf16 h[2]; unsigned int u; } pa, pb;
    pa.h[0] = (__bf16)va.x; pa.h[1] = (__bf16)va.y;
    pb.h[0] = (__bf16)vb.x; pb.h[1] = (__bf16)vb.y;
    *(unsigned int*)(fb + (size_t)i * D + lane * 2) = pa.u;
    *(unsigned int*)(fb + (size_t)(i + BATCH) * D + lane * 2) = pb.u;
    float na = va.x * va.x + va.y * va.y;
    float nb = vb.x * vb.x + vb.y * vb.y;
    const float dx = va.x - vb.x, dy = va.y - vb.y;
    float dd = dx * dx + dy * dy;
    #pragma unroll
    for (int m = 1; m <= 32; m <<= 1) {
        na += __shfl_xor(na, m); nb += __shfl_xor(nb, m); dd += __shfl_xor(dd, m);
    }
    if (lane == 0) {
        norms[i] = na; norms[i + BATCH] = nb;
        diag[i] = 1.f / (dd + 1.f);                   // exact fp32 cauchy diag of sim_ab
    }
}

// ---------------- pipelined 256x256 Gram-tile kernel: 3 tiles x 2 K-halves per block ----------------
__global__ __launch_bounds__(512, 2) void pipe_kernel(const unsigned short* __restrict__ fbf,
                                                      const float* __restrict__ norms,
                                                      float* __restrict__ Prow,
                                                      float* __restrict__ diag) {
    __shared__ __align__(16) unsigned char buf[2][65536];  // [A 32KB | B 32KB] x dbuf
    __shared__ float nrm[3][512];                          // per tile: rows[0..255], cols[256..511]
    __shared__ float rowbuf[256], colbuf[256];

    const int tid = threadIdx.x, wv = tid >> 6, lane = tid & 63;
    const int lr = lane & 15, hk = lane >> 4;
    const int qr = (wv >> 2) * 128, qc = (wv & 3) * 64;

    int TI[3], TJ[3];
    #pragma unroll
    for (int t = 0; t < 3; ++t) {
        const int id = blockIdx.x * 3 + t;
        int ti = (int)((sqrtf(8.f * (float)id + 1.f) - 1.f) * 0.5f);
        while ((ti + 1) * (ti + 2) / 2 <= id) ++ti;
        while (ti * (ti + 1) / 2 > id) --ti;
        TI[t] = ti; TJ[t] = id - ti * (ti + 1) / 2;
    }

    if (tid < 256) { rowbuf[tid] = 0.f; colbuf[tid] = 0.f; }
    #pragma unroll
    for (int t = 0; t < 3; ++t) {                       // norms -> LDS (no VMEM in epilogue later)
        const int panel = (tid < 256) ? TI[t] : TJ[t];
        nrm[t][tid] = norms[panel * BT + (tid & 255)];
    }
    LGKM0();

    f32x4 acc[8][4];

    auto ZERO = [&]() {
        #pragma unroll
        for (int i = 0; i < 8; ++i)
            #pragma unroll
            for (int j = 0; j < 4; ++j)
                acc[i][j] = (f32x4){0.f, 0.f, 0.f, 0.f};
    };

    // stage one 64KB unit (A-half + B-half of K) into buf[bsel]; 8 loads/thread
    auto STAGE = [&](int ti, int tj, int kp, int bsel) {
        const unsigned char* Ab = (const unsigned char*)fbf + (size_t)ti * BT * 256;
        const unsigned char* Bb = (const unsigned char*)fbf + (size_t)tj * BT * 256;
        #pragma unroll
        for (int it = 0; it < 4; ++it) {
            const int cid = it * 512 + tid, row = cid >> 3, p = cid & 7;
            const int sw = ((p ^ (row & 7)) << 4);
            load_lds16(Ab + row * 256 + kp * 128 + sw, &buf[bsel][it * 8192 + wv * 1024]);
        }
        #pragma unroll
        for (int it = 0; it < 4; ++it) {
            const int cid = it * 512 + tid, row = cid >> 3, p = cid & 7;
            const int sw = ((p ^ (row & 7)) << 4);
            load_lds16(Bb + row * 256 + kp * 128 + sw, &buf[bsel][32768 + it * 8192 + wv * 1024]);
        }
    };

    auto COMPUTE = [&](int bsel) {
        #pragma unroll
        for (int l = 0; l < 2; ++l) {
            const int c = l * 4 + hk;
            bf16x8 av[8], bv[4];
            #pragma unroll
            for (int fi = 0; fi < 8; ++fi) {
                const int row = qr + fi * 16 + lr;
                av[fi] = *(const bf16x8*)&buf[bsel][row * 128 + ((c ^ (row & 7)) << 4)];
            }
            #pragma unroll
            for (int fj = 0; fj < 4; ++fj) {
                const int row = qc + fj * 16 + lr;
                bv[fj] = *(const bf16x8*)&buf[bsel][32768 + row * 128 + ((c ^ (row & 7)) << 4)];
            }
            #pragma unroll
            for (int fi = 0; fi < 8; ++fi)
                #pragma unroll
                for (int fj = 0; fj < 4; ++fj)
                    acc[fi][fj] = __builtin_amdgcn_mfma_f32_16x16x32_bf16(av[fi], bv[fj], acc[fi][fj], 0, 0, 0);
        }
    };

    auto EPILOGUE = [&](int ti, int tj, const float* nr, bool last) {
        const bool diagblk = (ti == tj);
        float colN[4];
        #pragma unroll
        for (int fj = 0; fj < 4; ++fj) colN[fj] = nr[256 + qc + fj * 16 + lr];
        #pragma unroll
        for (int fi = 0; fi < 8; ++fi) {
            const int lrow = qr + fi * 16 + hk * 4;
            const f32x4 rN = *(const f32x4*)&nr[lrow];
            float rs[4] = {0.f, 0.f, 0.f, 0.f};
            #pragma unroll
            for (int fj = 0; fj < 4; ++fj) {
                const int lcol = qc + fj * 16 + lr;
                #pragma unroll
                for (int r = 0; r < 4; ++r) {
                    float sq = rN[r] + colN[fj] - 2.f * acc[fi][fj][r];
                    sq = fmaxf(sq, 0.f);
                    float sim = __builtin_amdgcn_rcpf(sq + 1.f);
                    if (diagblk && (lrow + r == lcol)) sim = 0.f;   // self-mask
                    rs[r] += sim;
                    acc[fi][fj][r] = sim;
                }
            }
            #pragma unroll
            for (int r = 0; r < 4; ++r) {
                rs[r] += __shfl_xor(rs[r], 1); rs[r] += __shfl_xor(rs[r], 2);
                rs[r] += __shfl_xor(rs[r], 4); rs[r] += __shfl_xor(rs[r], 8);
            }
            if (lr == 0) {
                #pragma unroll
                for (int r = 0; r < 4; ++r) atomicAdd(&rowbuf[lrow + r], rs[r]);
            }
        }
        #pragma unroll
        for (int fj = 0; fj < 4; ++fj) {
            float cs = 0.f;
            #pragma unroll
            for (int fi = 0; fi < 8; ++fi)
                #pragma unroll
                for (int r = 0; r < 4; ++r) cs += acc[fi][fj][r];
            cs += __shfl_xor(cs, 16); cs += __shfl_xor(cs, 32);
            if (hk == 0) atomicAdd(&colbuf[qc + fj * 16 + lr], cs);
        }
        LGKM0(); BAR();                                  // all LDS atomics visible
        if (tid < 256) {
            const float rv = rowbuf[tid], cv = colbuf[tid];
            rowbuf[tid] = 0.f; colbuf[tid] = 0.f;
            Prow[((size_t)ti * 64 + tj) * BT + tid] = rv;          // row slot tj
            Prow[((size_t)tj * 64 + 32 + ti) * BT + tid] = cv;     // col slot 32+ti (diag: unread slot)
        }
        if (!last) LGKM0();                              // drain re-zero before next tile's atomics
    };

    // ---- 6-unit software pipeline: issue early, counted vmcnt, raw barriers ----
    STAGE(TI[0], TJ[0], 0, 0);
    STAGE(TI[0], TJ[0], 1, 1);
    // tile 0
    ZERO();
    WAITV(8);  BAR(); COMPUTE(0); BAR();
    STAGE(TI[1], TJ[1], 0, 0);
    WAITV(8);  BAR(); COMPUTE(1); BAR();
    EPILOGUE(TI[0], TJ[0], &nrm[0][0], false);
    STAGE(TI[1], TJ[1], 1, 1);
    // tile 1
    ZERO();
    WAITV(20); BAR(); COMPUTE(0); BAR();
    STAGE(TI[2], TJ[2], 0, 0);
    WAITV(8);  BAR(); COMPUTE(1); BAR();
    EPILOGUE(TI[1], TJ[1], &nrm[1][0], false);
    STAGE(TI[2], TJ[2], 1, 1);
    // tile 2
    ZERO();
    WAITV(20); BAR(); COMPUTE(0); BAR();
    WAITV(0);  BAR(); COMPUTE(1); BAR();
    EPILOGUE(TI[2], TJ[2], &nrm[2][0], true);
}

// ---------------- finalize: sum valid Prow slots per row, logs, scalar ----------------
__global__ __launch_bounds__(256) void finalize_kernel(const float* __restrict__ Prow,
                                                       const float* __restrict__ diag,
                                                       float* __restrict__ out) {
    const int t = blockIdx.x;            // 32 row-panels
    const int r = threadIdx.x;           // 256 rows per panel
    const float* base = Prow + (size_t)t * 64 * BT + r;
    float s = 0.f;
    for (int k = 0; k <= t; ++k)       s += base[k * BT];       // row-side slots
    for (int k = 33 + t; k < 64; ++k)  s += base[k * BT];       // col-side slots
    const int i = t * BT + r;
    float term = 0.5f * __logf(s);
    if (i >= BATCH) term -= __logf(diag[i - BATCH]);
    #pragma unroll
    for (int m = 1; m <= 32; m <<= 1) term += __shfl_xor(term, m);
    __shared__ float sh[4];
    if ((threadIdx.x & 63) == 0) sh[threadIdx.x >> 6] = term;
    __syncthreads();
    if (threadIdx.x == 0)
        atomicAdd(out, (sh[0] + sh[1] + sh[2] + sh[3]) / (float)BATCH);
}

extern "C" void kernel_launch(void* const* d_in, const int* in_sizes, int n_in,
                              void* d_out, int out_size, void* d_ws, size_t ws_size,
                              hipStream_t stream) {
    const float* feat = (const float*)d_in[0];
    char* ws = (char*)d_ws;
    // ws layout: fbf16 2MB @0 | norms 32KB @2MB | diag 16KB | Prow 2MB
    unsigned short* fbf = (unsigned short*)ws;
    float* norms = (float*)(ws + (2u << 20));
    float* diag  = (float*)(ws + (2u << 20) + 32768);
    float* Prow  = (float*)(ws + (2u << 20) + 49152);
    float* out   = (float*)d_out;

    prep_kernel<<<BATCH / 4, 256, 0, stream>>>(feat, fbf, norms, diag, out);
    pipe_kernel<<<NBLK, 512, 0, stream>>>(fbf, norms, Prow, diag);
    finalize_kernel<<<NT, 256, 0, stream>>>(Prow, diag, out);
}

// Round 6
// 90.556 us; speedup vs baseline: 1.3925x; 1.1571x over previous
//
#include <hip/hip_runtime.h>
#include <hip/hip_bf16.h>

typedef __bf16 bf16x8 __attribute__((ext_vector_type(8)));
typedef float  f32x4  __attribute__((ext_vector_type(4)));

static constexpr int D     = 128;
static constexpr int BATCH = 4096;
static constexpr int N     = 8192;
static constexpr int BT    = 128;               // tile
static constexpr int NT    = N / BT;            // 64
static constexpr int TRI   = NT * (NT + 1) / 2; // 2080

__device__ __forceinline__ void load_lds16(const void* g, void* l) {
    __builtin_amdgcn_global_load_lds(
        (const __attribute__((address_space(1))) unsigned int*)g,
        (__attribute__((address_space(3))) unsigned int*)l, 16, 0, 0);
}

// ---------------- prep: bf16 convert + norms + exact fp32 ab-diag + zero out ----------------
__global__ __launch_bounds__(256) void prep_kernel(const float* __restrict__ f,
                                                   unsigned short* __restrict__ fb,
                                                   float* __restrict__ norms,
                                                   float* __restrict__ diag,
                                                   float* __restrict__ out) {
    if (blockIdx.x == 0 && threadIdx.x == 0) out[0] = 0.f;
    const int w = threadIdx.x >> 6, lane = threadIdx.x & 63;
    const int i = blockIdx.x * 4 + w;                 // 0..4095
    const float2 va = *(const float2*)(f + (size_t)i * D + lane * 2);
    const float2 vb = *(const float2*)(f + (size_t)(i + BATCH) * D + lane * 2);
    union { __bf16 h[2]; unsigned int u; } pa, pb;
    pa.h[0] = (__bf16)va.x; pa.h[1] = (__bf16)va.y;
    pb.h[0] = (__bf16)vb.x; pb.h[1] = (__bf16)vb.y;
    *(unsigned int*)(fb + (size_t)i * D + lane * 2) = pa.u;
    *(unsigned int*)(fb + (size_t)(i + BATCH) * D + lane * 2) = pb.u;
    float na = va.x * va.x + va.y * va.y;
    float nb = vb.x * vb.x + vb.y * vb.y;
    const float dx = va.x - vb.x, dy = va.y - vb.y;
    float dd = dx * dx + dy * dy;
    #pragma unroll
    for (int m = 1; m <= 32; m <<= 1) {
        na += __shfl_xor(na, m); nb += __shfl_xor(nb, m); dd += __shfl_xor(dd, m);
    }
    if (lane == 0) {
        norms[i] = na; norms[i + BATCH] = nb;
        diag[i] = 1.f / (dd + 1.f);                   // exact fp32 cauchy diag of sim_ab
    }
}

// ---------------- 128x128 Gram tile, 4 waves, one barrier, barrier-free epilogue ----------------
// P[t][k][0..127]: k<=t -> row-partials of tile(t,k); k>t -> col-partials of tile(k,t).
// Every slot written exactly once, non-atomically. finalize sums all 64 slots per row.
__global__ __launch_bounds__(256, 2) void tile_kernel(const unsigned short* __restrict__ fbf,
                                                      const float* __restrict__ norms,
                                                      float* __restrict__ P) {
    const int id = blockIdx.x;
    int ti = (int)((sqrtf(8.f * (float)id + 1.f) - 1.f) * 0.5f);
    while ((ti + 1) * (ti + 2) / 2 <= id) ++ti;
    while (ti * (ti + 1) / 2 > id) --ti;
    const int tj = id - ti * (ti + 1) / 2;
    const bool diagblk = (ti == tj);

    __shared__ __align__(16) unsigned char As[BT * 256];   // 32KB, 256B/row (full K)
    __shared__ __align__(16) unsigned char Bs[BT * 256];   // 32KB

    const int tid = threadIdx.x, wv = tid >> 6, lane = tid & 63;
    const int lr = lane & 15, hk = lane >> 4;

    // ---- stage both panels (single phase), pre-swizzled global src, linear LDS dst ----
    const unsigned char* Ab = (const unsigned char*)fbf + (size_t)ti * BT * 256;
    const unsigned char* Bb = (const unsigned char*)fbf + (size_t)tj * BT * 256;
    #pragma unroll
    for (int it = 0; it < 8; ++it) {
        const int cid = it * 256 + tid;
        const int row = cid >> 4, p = cid & 15;
        const int src = row * 256 + ((p ^ (row & 7)) << 4);
        load_lds16(Ab + src, As + it * 4096 + wv * 1024);
    }
    #pragma unroll
    for (int it = 0; it < 8; ++it) {
        const int cid = it * 256 + tid;
        const int row = cid >> 4, p = cid & 15;
        const int src = row * 256 + ((p ^ (row & 7)) << 4);
        load_lds16(Bb + src, Bs + it * 4096 + wv * 1024);
    }
    __syncthreads();

    // ---- compute: wave wv owns rows [wv*32, wv*32+32) x all 128 cols ----
    f32x4 acc[2][8];
    #pragma unroll
    for (int i = 0; i < 2; ++i)
        #pragma unroll
        for (int j = 0; j < 8; ++j)
            acc[i][j] = (f32x4){0.f, 0.f, 0.f, 0.f};

    #pragma unroll
    for (int ks = 0; ks < 4; ++ks) {
        const int c = ks * 4 + hk;
        bf16x8 av[2], bv[8];
        #pragma unroll
        for (int fi = 0; fi < 2; ++fi) {
            const int row = wv * 32 + fi * 16 + lr;
            av[fi] = *(const bf16x8*)(As + row * 256 + ((c ^ (row & 7)) << 4));
        }
        #pragma unroll
        for (int fj = 0; fj < 8; ++fj) {
            const int row = fj * 16 + lr;
            bv[fj] = *(const bf16x8*)(Bs + row * 256 + ((c ^ (row & 7)) << 4));
        }
        #pragma unroll
        for (int fi = 0; fi < 2; ++fi)
            #pragma unroll
            for (int fj = 0; fj < 8; ++fj)
                acc[fi][fj] = __builtin_amdgcn_mfma_f32_16x16x32_bf16(av[fi], bv[fj], acc[fi][fj], 0, 0, 0);
    }

    // ---- epilogue (no barriers): sim transform + in-wave row sums + col partials ----
    float colN[8];
    #pragma unroll
    for (int fj = 0; fj < 8; ++fj)
        colN[fj] = norms[tj * BT + fj * 16 + lr];

    float* PR = P + ((size_t)ti * NT + tj) * BT;   // row-partials slot
    #pragma unroll
    for (int fi = 0; fi < 2; ++fi) {
        const int lrow = wv * 32 + fi * 16 + hk * 4;          // + r
        const f32x4 rN = *(const f32x4*)(norms + ti * BT + lrow);
        f32x4 rs = (f32x4){0.f, 0.f, 0.f, 0.f};
        #pragma unroll
        for (int fj = 0; fj < 8; ++fj) {
            const int lcol = fj * 16 + lr;
            #pragma unroll
            for (int r = 0; r < 4; ++r) {
                float sq = rN[r] + colN[fj] - 2.f * acc[fi][fj][r];
                sq = fmaxf(sq, 0.f);
                float sim = __builtin_amdgcn_rcpf(sq + 1.f);
                if (diagblk && (lrow + r == lcol)) sim = 0.f;  // self-mask
                rs[r] += sim;
                acc[fi][fj][r] = sim;
            }
        }
        #pragma unroll
        for (int r = 0; r < 4; ++r) {
            rs[r] += __shfl_xor(rs[r], 1);
            rs[r] += __shfl_xor(rs[r], 2);
            rs[r] += __shfl_xor(rs[r], 4);
            rs[r] += __shfl_xor(rs[r], 8);
        }
        if (lr == 0)
            *(f32x4*)(PR + lrow) = rs;                         // 2x f32x4 per wave
    }

    // col partials: sum over fi,r then cross-quarter tree; hk==0 lanes write
    if (!diagblk) {
        float* PC = P + ((size_t)tj * NT + ti) * BT;           // col-partials slot
        #pragma unroll
        for (int fj = 0; fj < 8; ++fj) {
            float cs = 0.f;
            #pragma unroll
            for (int fi = 0; fi < 2; ++fi)
                #pragma unroll
                for (int r = 0; r < 4; ++r)
                    cs += acc[fi][fj][r];
            cs += __shfl_xor(cs, 16);
            cs += __shfl_xor(cs, 32);
            if (hk == 0)
                atomicAdd(&PC[fj * 16 + lr], cs);              // 4 waves -> same slot
        }
    }
}

// ---------------- finalize: uniform 64-slot sum per row, logs, scalar ----------------
__global__ __launch_bounds__(128) void finalize_kernel(const float* __restrict__ P,
                                                       const float* __restrict__ diag,
                                                       float* __restrict__ out) {
    const int t = blockIdx.x;            // 64 row-panels
    const int r = threadIdx.x;           // 128 rows per panel
    const float* base = P + (size_t)t * NT * BT + r;
    float s = 0.f;
    #pragma unroll 8
    for (int k = 0; k < NT; ++k) s += base[k * BT];
    const int i = t * BT + r;
    float term = 0.5f * __logf(s);
    if (i >= BATCH) term -= __logf(diag[i - BATCH]);
    #pragma unroll
    for (int m = 1; m <= 32; m <<= 1) term += __shfl_xor(term, m);
    if ((threadIdx.x & 63) == 0)
        atomicAdd(out, term / (float)BATCH);
}

// zero only the P tensor (2MB) + out; col slots are atomicAdd targets
__global__ __launch_bounds__(256) void zero_kernel(float* __restrict__ P) {
    ((f32x4*)P)[blockIdx.x * 256 + threadIdx.x] = (f32x4){0.f, 0.f, 0.f, 0.f};
}

extern "C" void kernel_launch(void* const* d_in, const int* in_sizes, int n_in,
                              void* d_out, int out_size, void* d_ws, size_t ws_size,
                              hipStream_t stream) {
    const float* feat = (const float*)d_in[0];
    char* ws = (char*)d_ws;
    // ws layout: fbf16 2MB @0 | norms 32KB | diag 16KB | P 2MB
    unsigned short* fbf = (unsigned short*)ws;
    float* norms = (float*)(ws + (2u << 20));
    float* diag  = (float*)(ws + (2u << 20) + 32768);
    float* P     = (float*)(ws + (2u << 20) + 49152);
    float* out   = (float*)d_out;

    zero_kernel<<<(NT * NT * BT) / 1024, 256, 0, stream>>>(P);
    prep_kernel<<<BATCH / 4, 256, 0, stream>>>(feat, fbf, norms, diag, out);
    tile_kernel<<<TRI, 256, 0, stream>>>(fbf, norms, P);
    finalize_kernel<<<NT, 128, 0, stream>>>(P, diag, out);
}

// Round 7
// 84.767 us; speedup vs baseline: 1.4876x; 1.0683x over previous
//
#include <hip/hip_runtime.h>
#include <hip/hip_bf16.h>

typedef __bf16 bf16x8 __attribute__((ext_vector_type(8)));
typedef float  f32x4  __attribute__((ext_vector_type(4)));

static constexpr int D     = 128;
static constexpr int BATCH = 4096;
static constexpr int N     = 8192;
static constexpr int BT    = 128;               // tile
static constexpr int NT    = N / BT;            // 64
static constexpr int TRI   = NT * (NT + 1) / 2; // 2080

__device__ __forceinline__ void load_lds16(const void* g, void* l) {
    __builtin_amdgcn_global_load_lds(
        (const __attribute__((address_space(1))) unsigned int*)g,
        (__attribute__((address_space(3))) unsigned int*)l, 16, 0, 0);
}

// ---------------- prep: bf16 convert + norms + exact fp32 ab-diag + zero out ----------------
__global__ __launch_bounds__(256) void prep_kernel(const float* __restrict__ f,
                                                   unsigned short* __restrict__ fb,
                                                   float* __restrict__ norms,
                                                   float* __restrict__ diag,
                                                   float* __restrict__ out) {
    if (blockIdx.x == 0 && threadIdx.x == 0) out[0] = 0.f;
    const int w = threadIdx.x >> 6, lane = threadIdx.x & 63;
    const int i = blockIdx.x * 4 + w;                 // 0..4095
    const float2 va = *(const float2*)(f + (size_t)i * D + lane * 2);
    const float2 vb = *(const float2*)(f + (size_t)(i + BATCH) * D + lane * 2);
    union { __bf16 h[2]; unsigned int u; } pa, pb;
    pa.h[0] = (__bf16)va.x; pa.h[1] = (__bf16)va.y;
    pb.h[0] = (__bf16)vb.x; pb.h[1] = (__bf16)vb.y;
    *(unsigned int*)(fb + (size_t)i * D + lane * 2) = pa.u;
    *(unsigned int*)(fb + (size_t)(i + BATCH) * D + lane * 2) = pb.u;
    float na = va.x * va.x + va.y * va.y;
    float nb = vb.x * vb.x + vb.y * vb.y;
    const float dx = va.x - vb.x, dy = va.y - vb.y;
    float dd = dx * dx + dy * dy;
    #pragma unroll
    for (int m = 1; m <= 32; m <<= 1) {
        na += __shfl_xor(na, m); nb += __shfl_xor(nb, m); dd += __shfl_xor(dd, m);
    }
    if (lane == 0) {
        norms[i] = na; norms[i + BATCH] = nb;
        diag[i] = 1.f / (dd + 1.f);                   // exact fp32 cauchy diag of sim_ab
    }
}

// ---------------- 128x128 Gram tile, K-phased 32KB staging, 4 blocks/CU ----------------
// P[t][k][0..127]: k<=t -> row-partials of tile(t,k); k>t -> col-partials of tile(k,t).
// Every slot written exactly once, non-atomically (diag blocks own slot k==t).
__global__ __launch_bounds__(256, 4) void tile_kernel(const unsigned short* __restrict__ fbf,
                                                      const float* __restrict__ norms,
                                                      float* __restrict__ P) {
    const int id = blockIdx.x;
    int ti = (int)((sqrtf(8.f * (float)id + 1.f) - 1.f) * 0.5f);
    while ((ti + 1) * (ti + 2) / 2 <= id) ++ti;
    while (ti * (ti + 1) / 2 > id) --ti;
    const int tj = id - ti * (ti + 1) / 2;
    const bool diagblk = (ti == tj);

    __shared__ __align__(16) unsigned char As[BT * 128];   // 16KB: half-K panel
    __shared__ __align__(16) unsigned char Bs[BT * 128];   // 16KB
    __shared__ float colbuf[BT];                           // 512B

    const int tid = threadIdx.x, wv = tid >> 6, lane = tid & 63;
    const int lr = lane & 15, hk = lane >> 4;

    if (tid < BT) colbuf[tid] = 0.f;

    const unsigned char* Ab = (const unsigned char*)fbf + (size_t)ti * BT * 256;
    const unsigned char* Bb = (const unsigned char*)fbf + (size_t)tj * BT * 256;

    f32x4 acc[2][8];
    #pragma unroll
    for (int i = 0; i < 2; ++i)
        #pragma unroll
        for (int j = 0; j < 8; ++j)
            acc[i][j] = (f32x4){0.f, 0.f, 0.f, 0.f};

    #pragma unroll
    for (int kp = 0; kp < 2; ++kp) {
        if (kp) __syncthreads();                 // LDS reuse fence
        // stage half-K: 4 loads/thread/panel; pre-swizzled src, linear LDS dst
        #pragma unroll
        for (int it = 0; it < 4; ++it) {
            const int cid = it * 256 + tid;
            const int row = cid >> 3, p = cid & 7;
            const int src = row * 256 + kp * 128 + ((p ^ (row & 7)) << 4);
            load_lds16(Ab + src, As + it * 4096 + wv * 1024);
        }
        #pragma unroll
        for (int it = 0; it < 4; ++it) {
            const int cid = it * 256 + tid;
            const int row = cid >> 3, p = cid & 7;
            const int src = row * 256 + kp * 128 + ((p ^ (row & 7)) << 4);
            load_lds16(Bb + src, Bs + it * 4096 + wv * 1024);
        }
        __syncthreads();

        // wave wv owns rows [wv*32, wv*32+32) x 128 cols; 2 k-steps per half
        #pragma unroll
        for (int ks = 0; ks < 2; ++ks) {
            const int c = ks * 4 + hk;
            bf16x8 av[2], bv[8];
            #pragma unroll
            for (int fi = 0; fi < 2; ++fi) {
                const int row = wv * 32 + fi * 16 + lr;
                av[fi] = *(const bf16x8*)(As + row * 128 + ((c ^ (row & 7)) << 4));
            }
            #pragma unroll
            for (int fj = 0; fj < 8; ++fj) {
                const int row = fj * 16 + lr;
                bv[fj] = *(const bf16x8*)(Bs + row * 128 + ((c ^ (row & 7)) << 4));
            }
            #pragma unroll
            for (int fi = 0; fi < 2; ++fi)
                #pragma unroll
                for (int fj = 0; fj < 8; ++fj)
                    acc[fi][fj] = __builtin_amdgcn_mfma_f32_16x16x32_bf16(av[fi], bv[fj], acc[fi][fj], 0, 0, 0);
        }
    }

    // ---- epilogue: sim transform + in-wave row sums + LDS-combined col partials ----
    float colN[8];
    #pragma unroll
    for (int fj = 0; fj < 8; ++fj)
        colN[fj] = norms[tj * BT + fj * 16 + lr];

    float* PR = P + ((size_t)ti * NT + tj) * BT;   // row-partials slot
    #pragma unroll
    for (int fi = 0; fi < 2; ++fi) {
        const int lrow = wv * 32 + fi * 16 + hk * 4;          // + r
        const f32x4 rN = *(const f32x4*)(norms + ti * BT + lrow);
        f32x4 rs = (f32x4){0.f, 0.f, 0.f, 0.f};
        #pragma unroll
        for (int fj = 0; fj < 8; ++fj) {
            const int lcol = fj * 16 + lr;
            #pragma unroll
            for (int r = 0; r < 4; ++r) {
                float sq = rN[r] + colN[fj] - 2.f * acc[fi][fj][r];
                sq = fmaxf(sq, 0.f);
                float sim = __builtin_amdgcn_rcpf(sq + 1.f);
                if (diagblk && (lrow + r == lcol)) sim = 0.f;  // self-mask
                rs[r] += sim;
                acc[fi][fj][r] = sim;
            }
        }
        #pragma unroll
        for (int r = 0; r < 4; ++r) {
            rs[r] += __shfl_xor(rs[r], 1);
            rs[r] += __shfl_xor(rs[r], 2);
            rs[r] += __shfl_xor(rs[r], 4);
            rs[r] += __shfl_xor(rs[r], 8);
        }
        if (lr == 0)
            *(f32x4*)(PR + lrow) = rs;                         // exact-once row writes
    }

    // col partials: wave-reduce then LDS atomics (4 waves), barrier, exact-once write
    if (!diagblk) {
        #pragma unroll
        for (int fj = 0; fj < 8; ++fj) {
            float cs = 0.f;
            #pragma unroll
            for (int fi = 0; fi < 2; ++fi)
                #pragma unroll
                for (int r = 0; r < 4; ++r)
                    cs += acc[fi][fj][r];
            cs += __shfl_xor(cs, 16);
            cs += __shfl_xor(cs, 32);
            if (hk == 0)
                atomicAdd(&colbuf[fj * 16 + lr], cs);
        }
        __syncthreads();
        if (tid < BT)
            P[((size_t)tj * NT + ti) * BT + tid] = colbuf[tid]; // exact-once col writes
    }
}

// ---------------- finalize: uniform 64-slot sum per row, logs, scalar ----------------
__global__ __launch_bounds__(128) void finalize_kernel(const float* __restrict__ P,
                                                       const float* __restrict__ diag,
                                                       float* __restrict__ out) {
    const int t = blockIdx.x;            // 64 row-panels
    const int r = threadIdx.x;           // 128 rows per panel
    const float* base = P + (size_t)t * NT * BT + r;
    float s = 0.f;
    #pragma unroll 8
    for (int k = 0; k < NT; ++k) s += base[k * BT];
    const int i = t * BT + r;
    float term = 0.5f * __logf(s);
    if (i >= BATCH) term -= __logf(diag[i - BATCH]);
    #pragma unroll
    for (int m = 1; m <= 32; m <<= 1) term += __shfl_xor(term, m);
    if ((threadIdx.x & 63) == 0)
        atomicAdd(out, term / (float)BATCH);
}

extern "C" void kernel_launch(void* const* d_in, const int* in_sizes, int n_in,
                              void* d_out, int out_size, void* d_ws, size_t ws_size,
                              hipStream_t stream) {
    const float* feat = (const float*)d_in[0];
    char* ws = (char*)d_ws;
    // ws layout: fbf16 2MB @0 | norms 32KB | diag 16KB | P 2MB
    unsigned short* fbf = (unsigned short*)ws;
    float* norms = (float*)(ws + (2u << 20));
    float* diag  = (float*)(ws + (2u << 20) + 32768);
    float* P     = (float*)(ws + (2u << 20) + 49152);
    float* out   = (float*)d_out;

    prep_kernel<<<BATCH / 4, 256, 0, stream>>>(feat, fbf, norms, diag, out);
    tile_kernel<<<TRI, 256, 0, stream>>>(fbf, norms, P);
    finalize_kernel<<<NT, 128, 0, stream>>>(P, diag, out);
}